// Round 1
// baseline (11.302 us; speedup 1.0000x reference)
//
#include <hip/hip_runtime.h>
#include <hip/hip_bf16.h>

// Quanvolution (16-qubit circuit) collapses analytically to per-wire cosines:
// after RY-encoding the state is a real product state; the fixed RandomLayer
// acts on disjoint wire sets {3},{7},{11},{0,8},{14},{5,12},{2},{9,1}, so
// <Z_i> factorizes:
//   untouched / RZ wires: cos(x_i)
//   RY(p) wires (2,7):    cos(x_i + p)
//   RX(p) wires (3,14):   cos(p) * cos(x_i)
//   CNOT targets (8,12,1):cos(x_ctrl) * cos(x_tgt)   (controls unchanged)
// Then feat(4,1024) @ head_w^T + bias -> log_softmax.

__global__ __launch_bounds__(256)
void quanv_fused_kernel(const float* __restrict__ x,
                        const float* __restrict__ qp,
                        const float* __restrict__ hw,
                        const float* __restrict__ hb,
                        float* __restrict__ out) {
    __shared__ float feat[4096];            // (4, 1024) features

    const int t = threadIdx.x;              // 0..255, one patch per thread
    const int b = t >> 6;                   // batch
    const int ij = t & 63;
    const int i = ij >> 3;                  // patch row
    const int j = ij & 7;                   // patch col

    // ---- phase 1: per-patch analytic measurements ----
    float a[16];
#pragma unroll
    for (int ch = 0; ch < 4; ++ch)
#pragma unroll
        for (int dy = 0; dy < 2; ++dy)
#pragma unroll
            for (int dx = 0; dx < 2; ++dx)
                a[ch * 4 + dy * 2 + dx] =
                    x[((b * 4 + ch) * 16 + (i * 2 + dy)) * 16 + (j * 2 + dx)];

    const float p0 = qp[0], p1 = qp[1], p3 = qp[3], p4 = qp[4]; // p2 (RZ) drops out

    float ca[16];
#pragma unroll
    for (int w = 0; w < 16; ++w) ca[w] = __cosf(a[w]);

    float m[16];
    m[0]  = ca[0];
    m[1]  = ca[9] * ca[1];
    m[2]  = __cosf(a[2] + p4);
    m[3]  = __cosf(p0) * ca[3];
    m[4]  = ca[4];
    m[5]  = ca[5];
    m[6]  = ca[6];
    m[7]  = __cosf(a[7] + p1);
    m[8]  = ca[0] * ca[8];
    m[9]  = ca[9];
    m[10] = ca[10];
    m[11] = ca[11];
    m[12] = ca[5] * ca[12];
    m[13] = ca[13];
    m[14] = __cosf(p3) * ca[14];
    m[15] = ca[15];

    // feat flat index: b*1024 + (i*8+j)*16 + w == t*16 + w
#pragma unroll
    for (int w = 0; w < 16; ++w) feat[t * 16 + w] = m[w];

    __syncthreads();

    // ---- phase 2: wave `b` computes 10 logits for batch row b ----
    const int wave = t >> 6;
    const int lane = t & 63;

    float logits[10];
#pragma unroll
    for (int k = 0; k < 10; ++k) {
        float s = 0.0f;
#pragma unroll
        for (int mblk = 0; mblk < 16; ++mblk) {
            const int f = lane + mblk * 64;
            s += feat[wave * 1024 + f] * hw[k * 1024 + f];
        }
#pragma unroll
        for (int off = 32; off > 0; off >>= 1) s += __shfl_down(s, off);
        logits[k] = s + hb[k];              // valid on lane 0
    }

    if (lane == 0) {
        float mx = logits[0];
#pragma unroll
        for (int k = 1; k < 10; ++k) mx = fmaxf(mx, logits[k]);
        float sum = 0.0f;
#pragma unroll
        for (int k = 0; k < 10; ++k) sum += __expf(logits[k] - mx);
        const float lse = __logf(sum) + mx;
#pragma unroll
        for (int k = 0; k < 10; ++k) out[wave * 10 + k] = logits[k] - lse;
    }
}

extern "C" void kernel_launch(void* const* d_in, const int* in_sizes, int n_in,
                              void* d_out, int out_size, void* d_ws, size_t ws_size,
                              hipStream_t stream) {
    const float* x  = (const float*)d_in[0];   // (4,4,16,16)
    const float* qp = (const float*)d_in[1];   // (5,)
    const float* hw = (const float*)d_in[2];   // (10,1024)
    const float* hb = (const float*)d_in[3];   // (10,)
    float* out = (float*)d_out;                // (4,10)

    quanv_fused_kernel<<<1, 256, 0, stream>>>(x, qp, hw, hb, out);
}

// Round 2
// 9.626 us; speedup vs baseline: 1.1741x; 1.1741x over previous
//
#include <hip/hip_runtime.h>
#include <hip/hip_bf16.h>

// Quanvolution (16-qubit circuit) collapses analytically to per-wire cosines:
// after RY-encoding the state is a real product state; the fixed RandomLayer
// acts on disjoint wire sets {3},{7},{11},{0,8},{14},{5,12},{2},{9,1}, so
// <Z_i> factorizes:
//   untouched / RZ wires: cos(x_i)
//   RY(p) wires (2,7):    cos(x_i + p)
//   RX(p) wires (3,14):   cos(p) * cos(x_i)
//   CNOT targets (8,12,1):cos(x_ctrl) * cos(x_tgt)   (controls unchanged)
// Then feat(4,1024) @ head_w^T + bias -> log_softmax.
//
// Key layout fact: lane l of wave b produces exactly feat[b*1024 + l*16 .. +15],
// and head_w rows index as k*1024 + l*16 + w, so the head GEMV runs fully
// in-register (per-lane 16-FMA partial + 6-step shuffle reduce). No LDS,
// no __syncthreads.

__global__ __launch_bounds__(256)
void quanv_fused_kernel(const float* __restrict__ x,
                        const float* __restrict__ qp,
                        const float* __restrict__ hw,
                        const float* __restrict__ hb,
                        float* __restrict__ out) {
    const int t = threadIdx.x;              // 0..255, one patch per thread
    const int b = t >> 6;                   // batch  (== wave id)
    const int lane = t & 63;                // patch id within batch
    const int i = lane >> 3;                // patch row
    const int j = lane & 7;                 // patch col

    // ---- phase 1: per-patch analytic measurements (in registers) ----
    float a[16];
#pragma unroll
    for (int ch = 0; ch < 4; ++ch)
#pragma unroll
        for (int dy = 0; dy < 2; ++dy) {
            const float2 v = *(const float2*)
                (x + ((b * 4 + ch) * 16 + (i * 2 + dy)) * 16 + j * 2);
            a[ch * 4 + dy * 2 + 0] = v.x;
            a[ch * 4 + dy * 2 + 1] = v.y;
        }

    const float p0 = qp[0], p1 = qp[1], p3 = qp[3], p4 = qp[4]; // p2 (RZ) drops out

    float ca[16];
#pragma unroll
    for (int w = 0; w < 16; ++w) ca[w] = __cosf(a[w]);

    float m[16];
    m[0]  = ca[0];
    m[1]  = ca[9] * ca[1];
    m[2]  = __cosf(a[2] + p4);
    m[3]  = __cosf(p0) * ca[3];
    m[4]  = ca[4];
    m[5]  = ca[5];
    m[6]  = ca[6];
    m[7]  = __cosf(a[7] + p1);
    m[8]  = ca[0] * ca[8];
    m[9]  = ca[9];
    m[10] = ca[10];
    m[11] = ca[11];
    m[12] = ca[5] * ca[12];
    m[13] = ca[13];
    m[14] = __cosf(p3) * ca[14];
    m[15] = ca[15];

    // ---- phase 2: in-register head GEMV, wave b -> logits[b][0..9] ----
    float logits[10];
#pragma unroll
    for (int k = 0; k < 10; ++k) {
        const float4* h4 = (const float4*)(hw + k * 1024 + lane * 16);
        float s = 0.0f;
#pragma unroll
        for (int q = 0; q < 4; ++q) {
            const float4 h = h4[q];
            s += m[q * 4 + 0] * h.x + m[q * 4 + 1] * h.y
               + m[q * 4 + 2] * h.z + m[q * 4 + 3] * h.w;
        }
#pragma unroll
        for (int off = 32; off > 0; off >>= 1) s += __shfl_down(s, off);
        logits[k] = s + hb[k];              // valid on lane 0
    }

    if (lane == 0) {
        float mx = logits[0];
#pragma unroll
        for (int k = 1; k < 10; ++k) mx = fmaxf(mx, logits[k]);
        float sum = 0.0f;
#pragma unroll
        for (int k = 0; k < 10; ++k) sum += __expf(logits[k] - mx);
        const float lse = __logf(sum) + mx;
#pragma unroll
        for (int k = 0; k < 10; ++k) out[b * 10 + k] = logits[k] - lse;
    }
}

extern "C" void kernel_launch(void* const* d_in, const int* in_sizes, int n_in,
                              void* d_out, int out_size, void* d_ws, size_t ws_size,
                              hipStream_t stream) {
    const float* x  = (const float*)d_in[0];   // (4,4,16,16)
    const float* qp = (const float*)d_in[1];   // (5,)
    const float* hw = (const float*)d_in[2];   // (10,1024)
    const float* hb = (const float*)d_in[3];   // (10,)
    float* out = (float*)d_out;                // (4,10)

    quanv_fused_kernel<<<1, 256, 0, stream>>>(x, qp, hw, hb, out);
}